// Round 3
// baseline (728.304 us; speedup 1.0000x reference)
//
#include <hip/hip_runtime.h>
#include <math.h>

// Problem constants
#define N_TOK 1024
#define TOPK  2
#define NEXP  16
#define HID   1024   // H
#define DIM   2048   // D
#define RANK  16
#define NPAIR (N_TOK * TOPK)
#define MOE_SCALE 0.25f
#define MAXTILES 31  // sum_e ceil(cnt_e/128) <= 15 + 16

typedef __attribute__((ext_vector_type(8))) short short8;
typedef __attribute__((ext_vector_type(4))) float floatx4;

static __device__ __forceinline__ unsigned short f2bf(float f) {
    union { float f; unsigned int u; } v; v.f = f;
    unsigned int u = v.u;
    u += 0x7fffu + ((u >> 16) & 1u);   // RNE
    return (unsigned short)(u >> 16);
}

static __device__ __forceinline__ short8 cvt8(float4 a, float4 b) {
    short8 o;
    o[0] = (short)f2bf(a.x); o[1] = (short)f2bf(a.y);
    o[2] = (short)f2bf(a.z); o[3] = (short)f2bf(a.w);
    o[4] = (short)f2bf(b.x); o[5] = (short)f2bf(b.y);
    o[6] = (short)f2bf(b.z); o[7] = (short)f2bf(b.w);
    return o;
}

// Fragment-buffer geometry: padded-tile-of-16-slots index T16 in [0, MAXTILES*8),
// per T16: [kChunk32][lane64][8 elems] bf16, i.e. one 1-KB block per (T16, C).
#define XG_T16_STRIDE   (64 * 64 * 8)   // DIM/32 = 64 k-chunks  (shorts)
#define ACT_T16_STRIDE  (32 * 64 * 8)   // HID/32 = 32 k-chunks  (shorts)

// ---------------------------------------------------------------------------
// Routing: sort pair indices by expert + dense (e,mt) worklist.
// ---------------------------------------------------------------------------
__global__ void k_routing(const int* __restrict__ ids,
                          int* __restrict__ offs,      // [NEXP+1]
                          int* __restrict__ sorted,    // [NPAIR]
                          int* __restrict__ tlist,     // [MAXTILES] (e<<8|mt)
                          int* __restrict__ tcount) {
    __shared__ int s_cnt[NEXP];
    __shared__ int s_off[NEXP + 1];
    int tid = threadIdx.x;
    if (tid < NEXP) s_cnt[tid] = 0;
    __syncthreads();
    for (int p = tid; p < NPAIR; p += blockDim.x) atomicAdd(&s_cnt[ids[p]], 1);
    __syncthreads();
    if (tid == 0) {
        int acc = 0;
        for (int e = 0; e < NEXP; ++e) { s_off[e] = acc; acc += s_cnt[e]; }
        s_off[NEXP] = acc;
        int t = 0;
        for (int e = 0; e < NEXP; ++e) {
            int c = s_off[e + 1] - s_off[e];
            for (int m = 0; m * 128 < c; ++m) tlist[t++] = (e << 8) | m;
        }
        *tcount = t;
    }
    __syncthreads();
    if (tid <= NEXP) offs[tid] = s_off[tid];
    if (tid < NEXP) s_cnt[tid] = s_off[tid];
    __syncthreads();
    for (int p = tid; p < NPAIR; p += blockDim.x) {
        int e = ids[p];
        int slot = atomicAdd(&s_cnt[e], 1);
        sorted[slot] = p;
    }
}

// ---------------------------------------------------------------------------
// Prepack: gather x rows by (expert,tile) and emit bf16 in MFMA-A-fragment
// layout: xg[(T16*64 + C)*64 + lane][8] with lane = (row&15) + 16*kquarter.
// Clamped (dup) rows for short tiles are materialized here once.
// ---------------------------------------------------------------------------
__global__ __launch_bounds__(256) void k_prep(
        const float* __restrict__ x, const int* __restrict__ offs,
        const int* __restrict__ sorted, const int* __restrict__ tlist,
        const int* __restrict__ tcount, unsigned short* __restrict__ xg) {
    int wt = blockIdx.x;
    if (wt >= *tcount) return;
    int code = tlist[wt];
    int e = code >> 8, mt = code & 255;
    int off = offs[e], cnt = offs[e + 1] - off;
    int tid = threadIdx.x, lane = tid & 63, wv = tid >> 6;
    int C = blockIdx.y * 4 + wv;           // 0..63 (k-chunk of 32)
    int r16 = lane & 15, lq = lane >> 4;
#pragma unroll
    for (int st = 0; st < 8; ++st) {
        int g = mt * 128 + st * 16 + r16; if (g >= cnt) g = cnt - 1;
        int tok = sorted[off + g] >> 1;
        const float* src = x + (size_t)tok * DIM + C * 32 + lq * 8;
        float4 a = *(const float4*)src;
        float4 b = *(const float4*)(src + 4);
        int T16 = wt * 8 + st;
        *(short8*)(xg + (size_t)T16 * XG_T16_STRIDE + (size_t)(C * 64 + lane) * 8)
            = cvt8(a, b);
    }
}

// ---------------------------------------------------------------------------
// Up-GEMM: barrier-free streaming. Block = 128 tok x 32 h-cols (gate+mul),
// wave = 64 tok x 16 h-cols. B (w_up) streamed HBM->reg->cvt->MFMA with
// ping-pong prefetch; A from xg fragments (contiguous); U (up_a) fused as a
// third MFMA column (accT). Single __syncthreads at epilogue for the t-spill.
// Writes act directly in k_down's A-fragment layout.
// ---------------------------------------------------------------------------
#define LOADB2(t, B, P0, P1) do {                                            \
    const float* _g = (P0) + (size_t)(t) * 64;                               \
    const float* _m = (P1) + (size_t)(t) * 64;                               \
    B[0] = *(const float4*)(_g);      B[1] = *(const float4*)(_g + 4);       \
    B[2] = *(const float4*)(_g + 32); B[3] = *(const float4*)(_g + 36);      \
    B[4] = *(const float4*)(_m);      B[5] = *(const float4*)(_m + 4);       \
    B[6] = *(const float4*)(_m + 32); B[7] = *(const float4*)(_m + 36);      \
} while (0)

#define COMP(t, B, ACC0, ACC1) do {                                          \
    short8 a0[4], a1[4];                                                     \
    _Pragma("unroll") for (int mf = 0; mf < 4; ++mf) {                       \
        a0[mf] = *(const short8*)(ap[mf] + (size_t)(2 * (t)) * 512);         \
        a1[mf] = *(const short8*)(ap[mf] + (size_t)(2 * (t) + 1) * 512);     \
    }                                                                        \
    float4 u0a = *(const float4*)(uq + (size_t)(t) * 64);                    \
    float4 u0b = *(const float4*)(uq + (size_t)(t) * 64 + 4);                \
    float4 u1a = *(const float4*)(uq + (size_t)(t) * 64 + 32);               \
    float4 u1b = *(const float4*)(uq + (size_t)(t) * 64 + 36);               \
    short8 f00 = cvt8(B[0], B[1]), f01 = cvt8(B[2], B[3]);                   \
    short8 f10 = cvt8(B[4], B[5]), f11 = cvt8(B[6], B[7]);                   \
    short8 fu0 = cvt8(u0a, u0b),   fu1 = cvt8(u1a, u1b);                     \
    _Pragma("unroll") for (int mf = 0; mf < 4; ++mf) {                       \
        ACC0[mf] = __builtin_amdgcn_mfma_f32_16x16x32_bf16(a0[mf], f00, ACC0[mf], 0, 0, 0); \
        ACC1[mf] = __builtin_amdgcn_mfma_f32_16x16x32_bf16(a0[mf], f10, ACC1[mf], 0, 0, 0); \
        accT[mf] = __builtin_amdgcn_mfma_f32_16x16x32_bf16(a0[mf], fu0, accT[mf], 0, 0, 0); \
        ACC0[mf] = __builtin_amdgcn_mfma_f32_16x16x32_bf16(a1[mf], f01, ACC0[mf], 0, 0, 0); \
        ACC1[mf] = __builtin_amdgcn_mfma_f32_16x16x32_bf16(a1[mf], f11, ACC1[mf], 0, 0, 0); \
        accT[mf] = __builtin_amdgcn_mfma_f32_16x16x32_bf16(a1[mf], fu1, accT[mf], 0, 0, 0); \
    }                                                                        \
} while (0)

#define G_PIPE(NC, ACC0, ACC1)                                               \
    {                                                                        \
        float4 B0[8], B1[8];                                                 \
        LOADB2(0, B0, bp0, bp1);                                             \
        _Pragma("unroll 1")                                                  \
        for (int t = 0; t + 2 < (NC); t += 2) {                              \
            LOADB2(t + 1, B1, bp0, bp1);                                     \
            COMP(t, B0, ACC0, ACC1);                                         \
            LOADB2(t + 2, B0, bp0, bp1);                                     \
            COMP(t + 1, B1, ACC0, ACC1);                                     \
        }                                                                    \
        LOADB2((NC) - 1, B1, bp0, bp1);                                      \
        COMP((NC) - 2, B0, ACC0, ACC1);                                      \
        COMP((NC) - 1, B1, ACC0, ACC1);                                      \
    }

__global__ __launch_bounds__(256, 2) void k_up(
        const unsigned short* __restrict__ xg, const float* __restrict__ w_up,
        const float* __restrict__ up_a, const float* __restrict__ up_b,
        const int* __restrict__ tlist, const int* __restrict__ tcount,
        unsigned short* __restrict__ actg) {
    int wt = blockIdx.x;
    if (wt >= *tcount) return;
    int code = tlist[wt];
    int e = code >> 8;
    int nt = blockIdx.y;                    // 0..31 : h-cols nt*32..+32

    int tid = threadIdx.x, lane = tid & 63, wv = tid >> 6;
    int tokg = wv & 1, hg = wv >> 1;
    int lm = lane & 15, lq = lane >> 4;

    // A fragment streams (4 m-frags of 16 slots each)
    const unsigned short* ap[4];
#pragma unroll
    for (int mf = 0; mf < 4; ++mf) {
        int T16 = wt * 8 + tokg * 4 + mf;
        ap[mf] = xg + (size_t)T16 * XG_T16_STRIDE + (size_t)lane * 8;
    }
    int h = nt * 32 + hg * 16 + lm;         // this thread's output column
    const float* bp0 = w_up + ((size_t)e * 2 * HID + h) * DIM + lq * 8;        // gate
    const float* bp1 = w_up + ((size_t)e * 2 * HID + HID + h) * DIM + lq * 8;  // mul
    const float* uq  = up_a + ((size_t)e * RANK + lm) * DIM + lq * 8;          // lora-A

    floatx4 zero = {0.f, 0.f, 0.f, 0.f};
    floatx4 accG[4], accM[4], accT[4];
#pragma unroll
    for (int i = 0; i < 4; ++i) { accG[i] = zero; accM[i] = zero; accT[i] = zero; }

    G_PIPE(32, accG, accM);

    // spill t = SCALE * (x . up_a^T) for the epilogue's full-rank dot
    __shared__ float t_s[128 * 16];
    if (wv < 2) {
#pragma unroll
        for (int mf = 0; mf < 4; ++mf)
#pragma unroll
            for (int j = 0; j < 4; ++j)
                t_s[(tokg * 64 + mf * 16 + lq * 4 + j) * 16 + lm] = MOE_SCALE * accT[mf][j];
    }
    __syncthreads();

    // epilogue: rank-16 LoRA + erf-gelu * mul -> actg (fragment layout)
    const float* b1 = up_b + ((size_t)e * 2 * HID + h) * RANK;
    const float* b2 = up_b + ((size_t)e * 2 * HID + HID + h) * RANK;
    float r1[RANK], r2[RANK];
#pragma unroll
    for (int i = 0; i < RANK; ++i) { r1[i] = b1[i]; r2[i] = b2[i]; }
    int C = h >> 5, lsub = 16 * ((h >> 3) & 3), el = h & 7;
#pragma unroll
    for (int mf = 0; mf < 4; ++mf) {
        int T16 = wt * 8 + tokg * 4 + mf;
        unsigned short* dst = actg + (size_t)T16 * ACT_T16_STRIDE + (size_t)C * 512 + el;
#pragma unroll
        for (int r = 0; r < 4; ++r) {
            int rl = tokg * 64 + mf * 16 + lq * 4 + r;
            const float* tv = t_s + rl * 16;
            float s1 = accG[mf][r], s2 = accM[mf][r];
#pragma unroll
            for (int j = 0; j < RANK; ++j) { s1 += tv[j] * r1[j]; s2 += tv[j] * r2[j]; }
            float gl = 0.5f * s1 * (1.f + erff(s1 * 0.70710678118654752f));
            dst[(size_t)(lq * 4 + r + lsub) * 8] = f2bf(gl * s2);
        }
    }
}

// ---------------------------------------------------------------------------
// Down-GEMM: same structure. Block = 128 tok x 64 d-cols, wave = 64 x 32.
// A = actg fragments; B = w_down streamed; U = down_a fused (accT -> t2).
// Epilogue: LoRA + topk-weight + atomic scatter-add.
// ---------------------------------------------------------------------------
__global__ __launch_bounds__(256, 2) void k_down(
        const unsigned short* __restrict__ actg, const float* __restrict__ w_down,
        const float* __restrict__ tw, const float* __restrict__ down_a,
        const float* __restrict__ down_b, const int* __restrict__ offs,
        const int* __restrict__ sorted, const int* __restrict__ tlist,
        const int* __restrict__ tcount, float* __restrict__ out) {
    int wt = blockIdx.x;
    if (wt >= *tcount) return;
    int code = tlist[wt];
    int e = code >> 8, mt = code & 255;
    int nt = blockIdx.y;                    // 0..31 : d-cols nt*64..+64
    int off = offs[e], cnt = offs[e + 1] - off;

    int tid = threadIdx.x, lane = tid & 63, wv = tid >> 6;
    int tokg = wv & 1, hg = wv >> 1;
    int lm = lane & 15, lq = lane >> 4;

    const unsigned short* ap[4];
#pragma unroll
    for (int mf = 0; mf < 4; ++mf) {
        int T16 = wt * 8 + tokg * 4 + mf;
        ap[mf] = actg + (size_t)T16 * ACT_T16_STRIDE + (size_t)lane * 8;
    }
    int d0 = nt * 64 + hg * 32 + lm;        // n-frag 0 col; n-frag 1 = d0+16
    const float* bp0 = w_down + ((size_t)e * DIM + d0) * HID + lq * 8;
    const float* bp1 = w_down + ((size_t)e * DIM + d0 + 16) * HID + lq * 8;
    const float* uq  = down_a + ((size_t)e * RANK + lm) * HID + lq * 8;

    floatx4 zero = {0.f, 0.f, 0.f, 0.f};
    floatx4 acc0[4], acc1[4], accT[4];
#pragma unroll
    for (int i = 0; i < 4; ++i) { acc0[i] = zero; acc1[i] = zero; accT[i] = zero; }

    G_PIPE(16, acc0, acc1);

    __shared__ float t_s[128 * 16];
    if (wv < 2) {
#pragma unroll
        for (int mf = 0; mf < 4; ++mf)
#pragma unroll
            for (int j = 0; j < 4; ++j)
                t_s[(tokg * 64 + mf * 16 + lq * 4 + j) * 16 + lm] = MOE_SCALE * accT[mf][j];
    }
    __syncthreads();

    const float* q0 = down_b + ((size_t)e * DIM + d0) * RANK;
    const float* q1 = down_b + ((size_t)e * DIM + d0 + 16) * RANK;
    float rb0[RANK], rb1[RANK];
#pragma unroll
    for (int i = 0; i < RANK; ++i) { rb0[i] = q0[i]; rb1[i] = q1[i]; }
#pragma unroll
    for (int mf = 0; mf < 4; ++mf) {
#pragma unroll
        for (int r = 0; r < 4; ++r) {
            int rl = tokg * 64 + mf * 16 + lq * 4 + r;
            int gg = mt * 128 + rl;
            if (gg < cnt) {
                int pp = sorted[off + gg];
                const float* tv = t_s + rl * 16;
                float v0 = acc0[mf][r], v1 = acc1[mf][r];
#pragma unroll
                for (int j = 0; j < RANK; ++j) { v0 += tv[j] * rb0[j]; v1 += tv[j] * rb1[j]; }
                float w = tw[pp];
                float* op = out + (size_t)(pp >> 1) * DIM;
                atomicAdd(op + d0, v0 * w);
                atomicAdd(op + d0 + 16, v1 * w);
            }
        }
    }
}

// ---------------------------------------------------------------------------
extern "C" void kernel_launch(void* const* d_in, const int* in_sizes, int n_in,
                              void* d_out, int out_size, void* d_ws, size_t ws_size,
                              hipStream_t stream) {
    const float* x      = (const float*)d_in[0];
    const float* tw     = (const float*)d_in[1];
    const int*   ids    = (const int*)d_in[2];
    const float* w_up   = (const float*)d_in[3];
    const float* w_down = (const float*)d_in[4];
    const float* up_a   = (const float*)d_in[5];
    const float* up_b   = (const float*)d_in[6];
    const float* down_a = (const float*)d_in[7];
    const float* down_b = (const float*)d_in[8];
    float* out = (float*)d_out;

    char* ws = (char*)d_ws;
    int* offs   = (int*)ws;                                  // 68 B
    int* tlist  = (int*)(ws + 1024);                         // 124 B
    int* tcount = (int*)(ws + 2048);                         // 4 B
    int* sorted = (int*)(ws + 4096);                         // 8 KB
    unsigned short* xg   = (unsigned short*)(ws + 65536);    // 248*64KiB ~= 15.5 MB
    unsigned short* actg = (unsigned short*)(ws + 65536 + (size_t)MAXTILES * 8 * XG_T16_STRIDE * 2);
                                                             // 248*32KiB ~= 7.75 MB

    hipMemsetAsync(d_out, 0, (size_t)out_size * sizeof(float), stream);

    k_routing<<<1, 256, 0, stream>>>(ids, offs, sorted, tlist, tcount);

    dim3 gprep(MAXTILES, 16);
    k_prep<<<gprep, 256, 0, stream>>>(x, offs, sorted, tlist, tcount, xg);

    dim3 gup(MAXTILES, 32);
    k_up<<<gup, 256, 0, stream>>>(xg, w_up, up_a, up_b, tlist, tcount, actg);

    dim3 gdn(MAXTILES, 32);
    k_down<<<gdn, 256, 0, stream>>>(actg, w_down, tw, down_a, down_b, offs, sorted, tlist, tcount, out);
}

// Round 5
// 663.310 us; speedup vs baseline: 1.0980x; 1.0980x over previous
//
#include <hip/hip_runtime.h>
#include <hip/hip_bf16.h>
#include <math.h>

// Problem constants
#define N_TOK 1024
#define TOPK  2
#define NEXP  16
#define HID   1024   // H
#define DIM   2048   // D
#define RANK  16
#define NPAIR (N_TOK * TOPK)
#define MOE_SCALE 0.25f
#define MAXTILES 31  // sum_e ceil(cnt_e/128) <= 15 + 16
#define NT16 (MAXTILES * 8)

typedef __attribute__((ext_vector_type(8))) short short8;
typedef __attribute__((ext_vector_type(4))) float floatx4;

static __device__ __forceinline__ unsigned short f2bf(float f) {
    union { __hip_bfloat16 b; unsigned short u; } v;
    v.b = __float2bfloat16(f);   // RNE, hardware cvt
    return v.u;
}

static __device__ __forceinline__ short8 cvt8(float4 a, float4 b) {
    short8 o;
    o[0] = (short)f2bf(a.x); o[1] = (short)f2bf(a.y);
    o[2] = (short)f2bf(a.z); o[3] = (short)f2bf(a.w);
    o[4] = (short)f2bf(b.x); o[5] = (short)f2bf(b.y);
    o[6] = (short)f2bf(b.z); o[7] = (short)f2bf(b.w);
    return o;
}

// Fragment-buffer geometry: T16 tile-of-16-slots index in [0, NT16).
// per T16: [kChunk32][lane64][8 elems] bf16 (1 KB per (T16, C)).
#define XG_T16_STRIDE   (64 * 64 * 8)   // DIM/32 chunks (shorts)
#define ACT_T16_STRIDE  (32 * 64 * 8)   // HID/32 chunks (shorts)

// ---------------------------------------------------------------------------
// Routing: sort pair indices by expert + dense (e,mt) worklist.
// ---------------------------------------------------------------------------
__global__ void k_routing(const int* __restrict__ ids,
                          int* __restrict__ offs,      // [NEXP+1]
                          int* __restrict__ sorted,    // [NPAIR]
                          int* __restrict__ tlist,     // [MAXTILES] (e<<8|mt)
                          int* __restrict__ tcount) {
    __shared__ int s_cnt[NEXP];
    __shared__ int s_off[NEXP + 1];
    int tid = threadIdx.x;
    if (tid < NEXP) s_cnt[tid] = 0;
    __syncthreads();
    for (int p = tid; p < NPAIR; p += blockDim.x) atomicAdd(&s_cnt[ids[p]], 1);
    __syncthreads();
    if (tid == 0) {
        int acc = 0;
        for (int e = 0; e < NEXP; ++e) { s_off[e] = acc; acc += s_cnt[e]; }
        s_off[NEXP] = acc;
        int t = 0;
        for (int e = 0; e < NEXP; ++e) {
            int c = s_off[e + 1] - s_off[e];
            for (int m = 0; m * 128 < c; ++m) tlist[t++] = (e << 8) | m;
        }
        *tcount = t;
    }
    __syncthreads();
    if (tid <= NEXP) offs[tid] = s_off[tid];
    if (tid < NEXP) s_cnt[tid] = s_off[tid];
    __syncthreads();
    for (int p = tid; p < NPAIR; p += blockDim.x) {
        int e = ids[p];
        int slot = atomicAdd(&s_cnt[e], 1);
        sorted[slot] = p;
    }
}

// ---------------------------------------------------------------------------
// Prepack: gather x rows by (expert,tile), emit bf16 MFMA-A fragments.
// ---------------------------------------------------------------------------
__global__ __launch_bounds__(256) void k_prep(
        const float* __restrict__ x, const int* __restrict__ offs,
        const int* __restrict__ sorted, const int* __restrict__ tlist,
        const int* __restrict__ tcount, unsigned short* __restrict__ xg) {
    int wt = blockIdx.x;
    if (wt >= *tcount) return;
    int code = tlist[wt];
    int e = code >> 8, mt = code & 255;
    int off = offs[e], cnt = offs[e + 1] - off;
    int tid = threadIdx.x, lane = tid & 63, wv = tid >> 6;
    int C = blockIdx.y * 4 + wv;           // 0..63 (k-chunk of 32)
    int r16 = lane & 15, lq = lane >> 4;
#pragma unroll
    for (int st = 0; st < 8; ++st) {
        int g = mt * 128 + st * 16 + r16; if (g >= cnt) g = cnt - 1;
        int tok = sorted[off + g] >> 1;
        const float* src = x + (size_t)tok * DIM + C * 32 + lq * 8;
        float4 a = *(const float4*)src;
        float4 b = *(const float4*)(src + 4);
        int T16 = wt * 8 + st;
        *(short8*)(xg + (size_t)T16 * XG_T16_STRIDE + (size_t)(C * 64 + lane) * 8)
            = cvt8(a, b);
    }
}

// ---------------------------------------------------------------------------
// LoRA-A dot kernels: t[slot16][rank] per T16 via MFMA over fragment buffer.
// One wave per T16. D layout: col(lm)=rank, row(lq*4+j)=slot.
// ---------------------------------------------------------------------------
__global__ __launch_bounds__(64) void k_tupg(
        const unsigned short* __restrict__ xg, const float* __restrict__ up_a,
        const int* __restrict__ tlist, const int* __restrict__ tcount,
        float* __restrict__ tup) {
    int T16 = blockIdx.x;
    if ((T16 >> 3) >= *tcount) return;
    int e = tlist[T16 >> 3] >> 8;
    int lane = threadIdx.x, lm = lane & 15, lq = lane >> 4;
    const unsigned short* ap = xg + (size_t)T16 * XG_T16_STRIDE + (size_t)lane * 8;
    const float* up = up_a + ((size_t)e * RANK + lm) * DIM + lq * 8;
    floatx4 zero = {0.f, 0.f, 0.f, 0.f};
    floatx4 a0 = zero, a1 = zero;
#pragma unroll 4
    for (int t = 0; t < 64; t += 2) {
        short8 f0 = *(const short8*)(ap + (size_t)t * 512);
        short8 f1 = *(const short8*)(ap + (size_t)(t + 1) * 512);
        float4 u00 = *(const float4*)(up + t * 32);
        float4 u01 = *(const float4*)(up + t * 32 + 4);
        float4 u10 = *(const float4*)(up + (t + 1) * 32);
        float4 u11 = *(const float4*)(up + (t + 1) * 32 + 4);
        a0 = __builtin_amdgcn_mfma_f32_16x16x32_bf16(f0, cvt8(u00, u01), a0, 0, 0, 0);
        a1 = __builtin_amdgcn_mfma_f32_16x16x32_bf16(f1, cvt8(u10, u11), a1, 0, 0, 0);
    }
#pragma unroll
    for (int j = 0; j < 4; ++j)
        tup[(size_t)T16 * 256 + (lq * 4 + j) * 16 + lm] = MOE_SCALE * (a0[j] + a1[j]);
}

__global__ __launch_bounds__(64) void k_t2g(
        const unsigned short* __restrict__ actg, const float* __restrict__ down_a,
        const int* __restrict__ tlist, const int* __restrict__ tcount,
        float* __restrict__ t2t) {
    int T16 = blockIdx.x;
    if ((T16 >> 3) >= *tcount) return;
    int e = tlist[T16 >> 3] >> 8;
    int lane = threadIdx.x, lm = lane & 15, lq = lane >> 4;
    const unsigned short* ap = actg + (size_t)T16 * ACT_T16_STRIDE + (size_t)lane * 8;
    const float* da = down_a + ((size_t)e * RANK + lm) * HID + lq * 8;
    floatx4 zero = {0.f, 0.f, 0.f, 0.f};
    floatx4 a0 = zero, a1 = zero;
#pragma unroll 4
    for (int t = 0; t < 32; t += 2) {
        short8 f0 = *(const short8*)(ap + (size_t)t * 512);
        short8 f1 = *(const short8*)(ap + (size_t)(t + 1) * 512);
        float4 u00 = *(const float4*)(da + t * 32);
        float4 u01 = *(const float4*)(da + t * 32 + 4);
        float4 u10 = *(const float4*)(da + (t + 1) * 32);
        float4 u11 = *(const float4*)(da + (t + 1) * 32 + 4);
        a0 = __builtin_amdgcn_mfma_f32_16x16x32_bf16(f0, cvt8(u00, u01), a0, 0, 0, 0);
        a1 = __builtin_amdgcn_mfma_f32_16x16x32_bf16(f1, cvt8(u10, u11), a1, 0, 0, 0);
    }
#pragma unroll
    for (int j = 0; j < 4; ++j)
        t2t[(size_t)T16 * 256 + (lq * 4 + j) * 16 + lm] = MOE_SCALE * (a0[j] + a1[j]);
}

// ---------------------------------------------------------------------------
// GEMM inner machinery: depth-1 double-buffered register prefetch for BOTH
// operands, consume-then-refill order. The pre-consume wait targets the
// OLDEST outstanding loads, leaving the next step's 8 loads in flight.
// No barriers in the main loop.
// ---------------------------------------------------------------------------
#define ISSUE_A(t, AR) do {                                                  \
    _Pragma("unroll") for (int mf = 0; mf < 4; ++mf)                         \
        AR[mf] = *(const short8*)(ap[mf] + (size_t)(t) * 512);               \
} while (0)

#define ISSUE_B(t, BR) do {                                                  \
    const float* _g = bpG + (size_t)(t) * 32;                                \
    const float* _m = bpM + (size_t)(t) * 32;                                \
    BR[0] = *(const float4*)_g; BR[1] = *(const float4*)(_g + 4);            \
    BR[2] = *(const float4*)_m; BR[3] = *(const float4*)(_m + 4);            \
} while (0)

#define CONSUME(AR, BR, ACCX, ACCY) do {                                     \
    short8 _fx = cvt8(BR[0], BR[1]);                                         \
    short8 _fy = cvt8(BR[2], BR[3]);                                         \
    _Pragma("unroll") for (int mf = 0; mf < 4; ++mf) {                       \
        ACCX[mf] = __builtin_amdgcn_mfma_f32_16x16x32_bf16(AR[mf], _fx, ACCX[mf], 0, 0, 0); \
        ACCY[mf] = __builtin_amdgcn_mfma_f32_16x16x32_bf16(AR[mf], _fy, ACCY[mf], 0, 0, 0); \
    }                                                                        \
} while (0)

#define G_PIPE(NC, ACCX, ACCY) do {                                          \
    short8 A0[4], A1[4];                                                     \
    float4 B0[4], B1[4];                                                     \
    ISSUE_A(0, A0); ISSUE_B(0, B0);                                          \
    ISSUE_A(1, A1); ISSUE_B(1, B1);                                          \
    _Pragma("unroll 1")                                                      \
    for (int t = 0; t < (NC); t += 2) {                                      \
        CONSUME(A0, B0, ACCX, ACCY);                                         \
        if (t + 2 < (NC)) { ISSUE_A(t + 2, A0); ISSUE_B(t + 2, B0); }        \
        CONSUME(A1, B1, ACCX, ACCY);                                         \
        if (t + 3 < (NC)) { ISSUE_A(t + 3, A1); ISSUE_B(t + 3, B1); }        \
    }                                                                        \
} while (0)

// XCD-bijective swizzle for 992 = 8 * 124 blocks: each XCD gets a contiguous
// run of (wt, nt) space -> xg/actg tile slices stay in one XCD's L2.
#define DECODE_WT_NT()                                                       \
    int lin = blockIdx.x;                                                    \
    int glob = (lin & 7) * 124 + (lin >> 3);                                 \
    int wt = glob >> 5, nt = glob & 31;

// ---------------------------------------------------------------------------
// Up-GEMM: wave = 64 toks x 16 h (gate+mul streams), NC=64 k-chunks.
// Barrier-free main loop; epilogue: rank-16 LoRA + erf-gelu*mul -> actg.
// ---------------------------------------------------------------------------
__global__ __launch_bounds__(256, 2) void k_up(
        const unsigned short* __restrict__ xg, const float* __restrict__ w_up,
        const float* __restrict__ tup, const float* __restrict__ up_b,
        const int* __restrict__ tlist, const int* __restrict__ tcount,
        unsigned short* __restrict__ actg) {
    DECODE_WT_NT();
    if (wt >= *tcount) return;
    int e = tlist[wt] >> 8;

    int tid = threadIdx.x, lane = tid & 63, wv = tid >> 6;
    int tokg = wv & 1, hg = wv >> 1;
    int lm = lane & 15, lq = lane >> 4;

    // stage this tile's t (lora-A dots) into LDS; consumed after the loop
    __shared__ float t_s[128 * 16];
    {
        const float* tsrc = tup + (size_t)wt * 2048;
#pragma unroll
        for (int j = 0; j < 8; ++j) t_s[tid * 8 + j] = tsrc[tid * 8 + j];
    }

    const unsigned short* ap[4];
#pragma unroll
    for (int mf = 0; mf < 4; ++mf) {
        int T16 = wt * 8 + tokg * 4 + mf;
        ap[mf] = xg + (size_t)T16 * XG_T16_STRIDE + (size_t)lane * 8;
    }
    int h = nt * 32 + hg * 16 + lm;
    const float* bpG = w_up + ((size_t)e * 2 * HID + h) * DIM + lq * 8;
    const float* bpM = w_up + ((size_t)e * 2 * HID + HID + h) * DIM + lq * 8;

    floatx4 zero = {0.f, 0.f, 0.f, 0.f};
    floatx4 accG[4], accM[4];
#pragma unroll
    for (int i = 0; i < 4; ++i) { accG[i] = zero; accM[i] = zero; }

    G_PIPE(64, accG, accM);

    __syncthreads();

    // epilogue: LoRA rank-16 + erf-gelu * mul -> actg (k_down fragment layout)
    const float* b1 = up_b + ((size_t)e * 2 * HID + h) * RANK;
    const float* b2 = up_b + ((size_t)e * 2 * HID + HID + h) * RANK;
    float r1[RANK], r2[RANK];
#pragma unroll
    for (int i = 0; i < RANK; ++i) { r1[i] = b1[i]; r2[i] = b2[i]; }
    int C = h >> 5, lsub = 16 * ((h >> 3) & 3), el = h & 7;
#pragma unroll
    for (int mf = 0; mf < 4; ++mf) {
        int T16 = wt * 8 + tokg * 4 + mf;
        unsigned short* dst = actg + (size_t)T16 * ACT_T16_STRIDE + (size_t)C * 512 + el;
#pragma unroll
        for (int r = 0; r < 4; ++r) {
            int rl = tokg * 64 + mf * 16 + lq * 4 + r;
            const float* tv = t_s + rl * 16;
            float s1 = accG[mf][r], s2 = accM[mf][r];
#pragma unroll
            for (int j = 0; j < RANK; ++j) { s1 += tv[j] * r1[j]; s2 += tv[j] * r2[j]; }
            float gl = 0.5f * s1 * (1.f + erff(s1 * 0.70710678118654752f));
            dst[(size_t)(lq * 4 + r + lsub) * 8] = f2bf(gl * s2);
        }
    }
}

// ---------------------------------------------------------------------------
// Down-GEMM: wave = 64 toks x 32 d (two 16-col streams), NC=32 k-chunks.
// Epilogue: LoRA + topk-weight + atomic scatter-add.
// ---------------------------------------------------------------------------
__global__ __launch_bounds__(256, 2) void k_down(
        const unsigned short* __restrict__ actg, const float* __restrict__ w_down,
        const float* __restrict__ tw, const float* __restrict__ t2t,
        const float* __restrict__ down_b, const int* __restrict__ offs,
        const int* __restrict__ sorted, const int* __restrict__ tlist,
        const int* __restrict__ tcount, float* __restrict__ out) {
    DECODE_WT_NT();
    if (wt >= *tcount) return;
    int code = tlist[wt];
    int e = code >> 8, mt = code & 255;
    int off = offs[e], cnt = offs[e + 1] - off;

    int tid = threadIdx.x, lane = tid & 63, wv = tid >> 6;
    int tokg = wv & 1, hg = wv >> 1;
    int lm = lane & 15, lq = lane >> 4;

    __shared__ float t_s[128 * 16];
    {
        const float* tsrc = t2t + (size_t)wt * 2048;
#pragma unroll
        for (int j = 0; j < 8; ++j) t_s[tid * 8 + j] = tsrc[tid * 8 + j];
    }

    const unsigned short* ap[4];
#pragma unroll
    for (int mf = 0; mf < 4; ++mf) {
        int T16 = wt * 8 + tokg * 4 + mf;
        ap[mf] = actg + (size_t)T16 * ACT_T16_STRIDE + (size_t)lane * 8;
    }
    int d0 = nt * 64 + hg * 32 + lm;        // second stream = d0 + 16
    const float* bpG = w_down + ((size_t)e * DIM + d0) * HID + lq * 8;
    const float* bpM = w_down + ((size_t)e * DIM + d0 + 16) * HID + lq * 8;

    floatx4 zero = {0.f, 0.f, 0.f, 0.f};
    floatx4 acc0[4], acc1[4];
#pragma unroll
    for (int i = 0; i < 4; ++i) { acc0[i] = zero; acc1[i] = zero; }

    G_PIPE(32, acc0, acc1);

    __syncthreads();

    const float* q0 = down_b + ((size_t)e * DIM + d0) * RANK;
    const float* q1 = down_b + ((size_t)e * DIM + d0 + 16) * RANK;
    float rb0[RANK], rb1[RANK];
#pragma unroll
    for (int i = 0; i < RANK; ++i) { rb0[i] = q0[i]; rb1[i] = q1[i]; }
#pragma unroll
    for (int mf = 0; mf < 4; ++mf) {
#pragma unroll
        for (int r = 0; r < 4; ++r) {
            int rl = tokg * 64 + mf * 16 + lq * 4 + r;
            int gg = mt * 128 + rl;
            if (gg < cnt) {
                int pp = sorted[off + gg];
                const float* tv = t_s + rl * 16;
                float v0 = acc0[mf][r], v1 = acc1[mf][r];
#pragma unroll
                for (int j = 0; j < RANK; ++j) { v0 += tv[j] * rb0[j]; v1 += tv[j] * rb1[j]; }
                float w = tw[pp];
                float* op = out + (size_t)(pp >> 1) * DIM;
                atomicAdd(op + d0, v0 * w);
                atomicAdd(op + d0 + 16, v1 * w);
            }
        }
    }
}

// ---------------------------------------------------------------------------
extern "C" void kernel_launch(void* const* d_in, const int* in_sizes, int n_in,
                              void* d_out, int out_size, void* d_ws, size_t ws_size,
                              hipStream_t stream) {
    const float* x      = (const float*)d_in[0];
    const float* tw     = (const float*)d_in[1];
    const int*   ids    = (const int*)d_in[2];
    const float* w_up   = (const float*)d_in[3];
    const float* w_down = (const float*)d_in[4];
    const float* up_a   = (const float*)d_in[5];
    const float* up_b   = (const float*)d_in[6];
    const float* down_a = (const float*)d_in[7];
    const float* down_b = (const float*)d_in[8];
    float* out = (float*)d_out;

    char* ws = (char*)d_ws;
    int*   offs   = (int*)ws;                            // 68 B
    int*   tlist  = (int*)(ws + 1024);                   // 124 B
    int*   tcount = (int*)(ws + 2048);                   // 4 B
    int*   sorted = (int*)(ws + 4096);                   // 8 KB
    float* tup    = (float*)(ws + 16384);                // NT16*256*4 = 254 KB
    float* t2t    = (float*)(ws + 16384 + 262144);       // 254 KB
    unsigned short* xg   = (unsigned short*)(ws + 1048576);                   // 15.5 MB
    unsigned short* actg = (unsigned short*)(ws + 1048576
                              + (size_t)NT16 * XG_T16_STRIDE * 2);            // 7.75 MB

    hipMemsetAsync(d_out, 0, (size_t)out_size * sizeof(float), stream);

    k_routing<<<1, 256, 0, stream>>>(ids, offs, sorted, tlist, tcount);

    dim3 gprep(MAXTILES, 16);
    k_prep<<<gprep, 256, 0, stream>>>(x, offs, sorted, tlist, tcount, xg);

    k_tupg<<<NT16, 64, 0, stream>>>(xg, up_a, tlist, tcount, tup);

    k_up<<<MAXTILES * 32, 256, 0, stream>>>(xg, w_up, tup, up_b, tlist, tcount, actg);

    k_t2g<<<NT16, 64, 0, stream>>>(actg, down_a, tlist, tcount, t2t);

    k_down<<<MAXTILES * 32, 256, 0, stream>>>(actg, w_down, tw, t2t, down_b,
                                              offs, sorted, tlist, tcount, out);
}